// Round 4
// baseline (1292.901 us; speedup 1.0000x reference)
//
#include <hip/hip_runtime.h>

// B=2, N=2048, K=32, H=256.  Reference dtypes ambiguous (fp32 vs harness-bf16):
// this version RUNTIME-DETECTS dtype (and E_idx int32 vs int64) and sanitizes
// every decoded value. Scratch lives inside the h_E output region (derived on
// device from the dtype flag); no d_ws usage.

using u16 = unsigned short;
using bf16x8 = __attribute__((ext_vector_type(8))) short;
using f32x4  = __attribute__((ext_vector_type(4))) float;

__device__ __forceinline__ float bf2f(u16 h) {
    union { unsigned u; float f; } v; v.u = (unsigned)h << 16; return v.f;
}
__device__ __forceinline__ u16 f2bf(float f) {
    union { float f; unsigned u; } v; v.f = f;
    unsigned r = v.u + 0x7fffu + ((v.u >> 16) & 1u);
    return (u16)(r >> 16);
}
__device__ __forceinline__ float gelu_f(float x) {
    if (!(x > -10.0f)) return 0.0f;   // also catches NaN
    return 0.5f * x * (1.0f + erff(x * 0.70710678118654752f));
}
__device__ __forceinline__ u16 scrub16(u16 h) {        // bf16 NaN/Inf -> 0
    return ((h & 0x7F80u) == 0x7F80u) ? (u16)0 : h;
}
__device__ __forceinline__ float sanef(float x) {
    return (x == x && x < 1e30f && x > -1e30f) ? x : 0.0f;
}

// dtype probe: if bf16, the LOW u16 of each dword is a plausible bf16 normal;
// if fp32, low u16s are mantissa bits (uniform) -> implausible w.h.p.
__device__ __forceinline__ int detect_f32(const void* probe) {
    const u16* p = (const u16*)probe;
    int ok = 1;
    #pragma unroll
    for (int i = 0; i < 16; ++i) {
        int e = (p[2 * i] >> 7) & 0xFF;
        ok &= (e >= 100) & (e <= 140);
    }
    return !ok;
}
// int64 E_idx: high dwords of first 4 elements are all zero.
__device__ __forceinline__ int detect_i64(const void* eidx) {
    const int* p = (const int*)eidx;
    return (p[1] | p[3] | p[5] | p[7]) == 0;
}
__device__ __forceinline__ int loadidx(const void* base, int i, int i64) {
    int v = i64 ? (int)((const long long*)base)[i] : ((const int*)base)[i];
    return v & 2047;
}
__device__ __forceinline__ float loadf(const void* base, size_t i, int f32) {
    return sanef(f32 ? ((const float*)base)[i] : bf2f(((const u16*)base)[i]));
}
__device__ __forceinline__ void storef(void* base, size_t i, int f32, float v) {
    if (f32) ((float*)base)[i] = v; else ((u16*)base)[i] = f2bf(v);
}
// stage 8 consecutive elements (idx multiple of 8) as scrubbed bf16 into LDS
__device__ __forceinline__ void stage8(const void* base, size_t idx, int f32, u16* dst) {
    u16 t[8];
    if (f32) {
        const float* p = (const float*)base + idx;
        f32x4 a = *(const f32x4*)p;
        f32x4 b = *(const f32x4*)(p + 4);
        t[0]=f2bf(sanef(a[0])); t[1]=f2bf(sanef(a[1]));
        t[2]=f2bf(sanef(a[2])); t[3]=f2bf(sanef(a[3]));
        t[4]=f2bf(sanef(b[0])); t[5]=f2bf(sanef(b[1]));
        t[6]=f2bf(sanef(b[2])); t[7]=f2bf(sanef(b[3]));
    } else {
        *(uint4*)t = *(const uint4*)((const u16*)base + idx);
        #pragma unroll
        for (int i = 0; i < 8; ++i) t[i] = scrub16(t[i]);
    }
    *(uint4*)dst = *(uint4*)t;
}
// stage one 256x32 weight slice (row=tid, cols k0..k0+32) into sW [256][40]
__device__ __forceinline__ void stage_w(const void* B, int ldb, size_t boff, int k0,
                                        int f32, u16* sW, int tid) {
    #pragma unroll
    for (int j = 0; j < 4; ++j)
        stage8(B, boff + (size_t)tid * ldb + k0 + j * 8, f32, sW + tid * 40 + j * 8);
}

// one K-step of MFMAs: wave (wm,wn) covers rows wm*32..+32, cols wn*128..+128
__device__ __forceinline__ void mma_tiles(const u16* aBase, int aStride, int aOff,
                                          const u16* sW, int wm, int wn, int l15, int quad,
                                          f32x4 acc[2][8]) {
    bf16x8 a0 = *(const bf16x8*)(aBase + (wm * 32 + l15) * aStride + aOff + quad * 8);
    bf16x8 a1 = *(const bf16x8*)(aBase + (wm * 32 + 16 + l15) * aStride + aOff + quad * 8);
    #pragma unroll
    for (int nb = 0; nb < 8; ++nb) {
        bf16x8 bfr = *(const bf16x8*)(sW + (wn * 128 + nb * 16 + l15) * 40 + quad * 8);
        acc[0][nb] = __builtin_amdgcn_mfma_f32_16x16x32_bf16(a0, bfr, acc[0][nb], 0, 0, 0);
        acc[1][nb] = __builtin_amdgcn_mfma_f32_16x16x32_bf16(a1, bfr, acc[1][nb], 0, 0, 0);
    }
}

// Fused 3-layer message MLP, 64 edge rows/block; layer 1 = full 768-wide concat.
// MODE 0: node message -> Msum[node][256] (fp32 scratch) ; MODE 1: outE = LN(hE + m3)
template<int MODE>
__global__ __launch_bounds__(256, 2) void msg_fused(
    const void* probe, const void* hVcur, const void* hE, const void* Eidx,
    const void* W1, const void* b1, const void* W2, const void* b2,
    const void* W3, const void* b3, const void* lng, const void* lnb,
    void* dout)
{
    __shared__ u16 sT[64 * 264];
    __shared__ u16 sW[256 * 40];
    __shared__ u16 sA[64 * 40];

    const int f32 = detect_f32(probe);
    const int i64 = detect_i64(Eidx);
    char* outEb = (char*)dout + (size_t)1048576 * (f32 ? 4 : 2);

    const int tid  = threadIdx.x;
    const int lane = tid & 63;
    const int wv   = tid >> 6;
    const int wm   = wv & 1;
    const int wn   = wv >> 1;
    const int l15  = lane & 15;
    const int quad = lane >> 4;
    const int m0   = blockIdx.x * 64;

    const int r = tid >> 2, c = tid & 3;
    const int mg_r   = m0 + r;
    const int node_r = mg_r >> 5;
    const int bidx_r = mg_r >> 16;
    const int jn_r   = bidx_r * 2048 + loadidx(Eidx, mg_r, i64);
    const size_t selfOff = (size_t)node_r * 256;
    const size_t eOff    = (size_t)mg_r   * 256;
    const size_t nbrOff  = (size_t)jn_r   * 256;

    int col[8];
    #pragma unroll
    for (int nb = 0; nb < 8; ++nb) col[nb] = wn * 128 + nb * 16 + l15;

    const f32x4 vzero = {0.f, 0.f, 0.f, 0.f};
    f32x4 acc[2][8];
    #pragma unroll
    for (int mb = 0; mb < 2; ++mb)
        #pragma unroll
        for (int nb = 0; nb < 8; ++nb) acc[mb][nb] = vzero;

    // ---- layer 1: gelu([hv_self | hE | hv_nbr] @ W1^T + b1) -> sT ----
    for (int ks = 0; ks < 24; ++ks) {
        const void* abase = (ks >= 8 && ks < 16) ? hE : hVcur;
        const size_t aoff = ((ks < 8) ? selfOff : (ks < 16 ? eOff : nbrOff))
                          + (size_t)(ks & 7) * 32 + c * 8;
        stage_w(W1, 768, 0, ks * 32, f32, sW, tid);
        stage8(abase, aoff, f32, sA + r * 40 + c * 8);
        __syncthreads();
        mma_tiles(sA, 40, 0, sW, wm, wn, l15, quad, acc);
        __syncthreads();
    }
    {
        float bv[8];
        #pragma unroll
        for (int nb = 0; nb < 8; ++nb) bv[nb] = loadf(b1, col[nb], f32);
        #pragma unroll
        for (int mb = 0; mb < 2; ++mb)
            #pragma unroll
            for (int rr = 0; rr < 4; ++rr) {
                const int row = wm * 32 + mb * 16 + quad * 4 + rr;
                #pragma unroll
                for (int nb = 0; nb < 8; ++nb)
                    sT[row * 264 + col[nb]] = f2bf(gelu_f(acc[mb][nb][rr] + bv[nb]));
            }
    }
    __syncthreads();

    // ---- layer 2 ----
    #pragma unroll
    for (int mb = 0; mb < 2; ++mb)
        #pragma unroll
        for (int nb = 0; nb < 8; ++nb) acc[mb][nb] = vzero;
    for (int ks = 0; ks < 8; ++ks) {
        stage_w(W2, 256, 0, ks * 32, f32, sW, tid);
        __syncthreads();
        mma_tiles(sT, 264, ks * 32, sW, wm, wn, l15, quad, acc);
        __syncthreads();
    }
    {
        float bv[8];
        #pragma unroll
        for (int nb = 0; nb < 8; ++nb) bv[nb] = loadf(b2, col[nb], f32);
        #pragma unroll
        for (int mb = 0; mb < 2; ++mb)
            #pragma unroll
            for (int rr = 0; rr < 4; ++rr) {
                const int row = wm * 32 + mb * 16 + quad * 4 + rr;
                #pragma unroll
                for (int nb = 0; nb < 8; ++nb)
                    sT[row * 264 + col[nb]] = f2bf(gelu_f(acc[mb][nb][rr] + bv[nb]));
            }
    }
    __syncthreads();

    // ---- layer 3 ----
    #pragma unroll
    for (int mb = 0; mb < 2; ++mb)
        #pragma unroll
        for (int nb = 0; nb < 8; ++nb) acc[mb][nb] = vzero;
    for (int ks = 0; ks < 8; ++ks) {
        stage_w(W3, 256, 0, ks * 32, f32, sW, tid);
        __syncthreads();
        mma_tiles(sT, 264, ks * 32, sW, wm, wn, l15, quad, acc);
        __syncthreads();
    }

    if (MODE == 0) {
        float* Msum = (float*)outEb;
        const int node0 = (m0 >> 5) + wm;
        #pragma unroll
        for (int nb = 0; nb < 8; ++nb) {
            float s = acc[0][nb][0] + acc[0][nb][1] + acc[0][nb][2] + acc[0][nb][3]
                    + acc[1][nb][0] + acc[1][nb][1] + acc[1][nb][2] + acc[1][nb][3];
            s += __shfl_xor(s, 16);
            s += __shfl_xor(s, 32);
            if (quad == 0)
                Msum[(size_t)node0 * 256 + col[nb]] = s + 32.0f * loadf(b3, col[nb], f32);
        }
    } else {
        float* sLN = (float*)sA;
        float b3v[8], gv[8], bv[8];
        #pragma unroll
        for (int nb = 0; nb < 8; ++nb) {
            b3v[nb] = loadf(b3, col[nb], f32);
            gv[nb]  = loadf(lng, col[nb], f32);
            bv[nb]  = loadf(lnb, col[nb], f32);
        }
        #pragma unroll
        for (int mb = 0; mb < 2; ++mb)
            #pragma unroll
            for (int rr = 0; rr < 4; ++rr) {
                const int row = wm * 32 + mb * 16 + quad * 4 + rr;
                const size_t ebase = (size_t)(m0 + row) * 256;
                float ps = 0.f, pq = 0.f;
                #pragma unroll
                for (int nb = 0; nb < 8; ++nb) {
                    float v = acc[mb][nb][rr] + b3v[nb] + loadf(hE, ebase + col[nb], f32);
                    acc[mb][nb][rr] = v;
                    ps += v; pq += v * v;
                }
                ps += __shfl_xor(ps, 1);  pq += __shfl_xor(pq, 1);
                ps += __shfl_xor(ps, 2);  pq += __shfl_xor(pq, 2);
                ps += __shfl_xor(ps, 4);  pq += __shfl_xor(pq, 4);
                ps += __shfl_xor(ps, 8);  pq += __shfl_xor(pq, 8);
                if (l15 == 0) {
                    sLN[(wn * 64 + row) * 2]     = ps;
                    sLN[(wn * 64 + row) * 2 + 1] = pq;
                }
            }
        __syncthreads();
        #pragma unroll
        for (int mb = 0; mb < 2; ++mb)
            #pragma unroll
            for (int rr = 0; rr < 4; ++rr) {
                const int row = wm * 32 + mb * 16 + quad * 4 + rr;
                const float ts = sLN[row * 2]     + sLN[(64 + row) * 2];
                const float tq = sLN[row * 2 + 1] + sLN[(64 + row) * 2 + 1];
                const float mu   = ts * (1.0f / 256.0f);
                const float var  = fmaxf(tq * (1.0f / 256.0f) - mu * mu, 0.0f);
                const float rstd = rsqrtf(var + 1e-5f);
                const size_t obase = (size_t)(m0 + row) * 256;
                #pragma unroll
                for (int nb = 0; nb < 8; ++nb)
                    storef(outEb, obase + col[nb], f32,
                           (acc[mb][nb][rr] - mu) * rstd * gv[nb] + bv[nb]);
            }
    }
}

// FFN GEMMs over scratch. PHASE 0: Ubuf = gelu(hV1 @ Win^T + bin) (bf16 scratch),
// grid (64,2). PHASE 1: dh = Ubuf @ Wout^T + bout (fp32 scratch), grid (64,1).
template<int PHASE>
__global__ __launch_bounds__(256, 2) void gemm_ffn(
    const void* probe, void* dout, const void* Bw, const void* bias)
{
    __shared__ u16 sW[256 * 40];
    __shared__ u16 sA[64 * 40];

    const int f32 = detect_f32(probe);
    char* outEb = (char*)dout + (size_t)1048576 * (f32 ? 4 : 2);
    u16*   hV1  = (u16*)(outEb + (4u << 20));
    u16*   Ubuf = (u16*)(outEb + (6u << 20));
    float* dh   = (float*)(outEb + (10u << 20));

    const int tid  = threadIdx.x;
    const int lane = tid & 63;
    const int wv   = tid >> 6;
    const int wm   = wv & 1;
    const int wn   = wv >> 1;
    const int l15  = lane & 15;
    const int quad = lane >> 4;
    const int m0   = blockIdx.x * 64;
    const int colbase = blockIdx.y * 256;
    const size_t boff = (size_t)blockIdx.y * 256 * 256;   // PHASE 0 only

    const int Kdim = (PHASE == 0) ? 256 : 512;
    const int ldb  = (PHASE == 0) ? 256 : 512;
    const u16* A   = (PHASE == 0) ? hV1 : Ubuf;
    const int lda  = (PHASE == 0) ? 256 : 512;

    int col[8];
    #pragma unroll
    for (int nb = 0; nb < 8; ++nb) col[nb] = wn * 128 + nb * 16 + l15;

    const f32x4 vzero = {0.f, 0.f, 0.f, 0.f};
    f32x4 acc[2][8];
    #pragma unroll
    for (int mb = 0; mb < 2; ++mb)
        #pragma unroll
        for (int nb = 0; nb < 8; ++nb) acc[mb][nb] = vzero;

    const int r = tid >> 2, c = tid & 3;
    for (int ks = 0; ks < (Kdim >> 5); ++ks) {
        const int k0 = ks * 32;
        stage_w(Bw, ldb, boff, k0, f32, sW, tid);
        stage8(A, (size_t)(m0 + r) * lda + k0 + c * 8, 0, sA + r * 40 + c * 8);
        __syncthreads();
        mma_tiles(sA, 40, 0, sW, wm, wn, l15, quad, acc);
        __syncthreads();
    }

    #pragma unroll
    for (int mb = 0; mb < 2; ++mb)
        #pragma unroll
        for (int rr = 0; rr < 4; ++rr) {
            const int row = m0 + wm * 32 + mb * 16 + quad * 4 + rr;
            #pragma unroll
            for (int nb = 0; nb < 8; ++nb) {
                const int gcol = colbase + col[nb];
                const float v = acc[mb][nb][rr] + loadf(bias, gcol, f32);
                if (PHASE == 0)
                    Ubuf[(size_t)row * 512 + gcol] = f2bf(gelu_f(v));
                else
                    dh[(size_t)row * 256 + gcol] = v;
            }
        }
}

// LayerNorm rows of 256. PHASE 0: hV1 = LN(hV + Msum/16)   (scratch bf16 out)
//                        PHASE 1: outV = LN(hV1 + dh)      (adaptive out)
template<int PHASE>
__global__ __launch_bounds__(256) void ln_k(
    const void* probe, void* dout, const void* g, const void* b)
{
    const int f32 = detect_f32(probe);
    char* outEb = (char*)dout + (size_t)1048576 * (f32 ? 4 : 2);
    float* Msum = (float*)outEb;
    u16*   hV1  = (u16*)(outEb + (4u << 20));
    float* dh   = (float*)(outEb + (10u << 20));

    const int lane = threadIdx.x & 63;
    const int wvi  = threadIdx.x >> 6;
    const int row  = blockIdx.x * 4 + wvi;
    const size_t base = (size_t)row * 256 + lane * 4;

    float v[4];
    #pragma unroll
    for (int i = 0; i < 4; ++i) {
        float xb = (PHASE == 0) ? loadf(probe, base + i, f32) : bf2f(hV1[base + i]);
        float xf = (PHASE == 0) ? sanef(Msum[base + i]) * (1.0f / 16.0f)
                                : sanef(dh[base + i]);
        v[i] = xb + xf;
    }
    float s = v[0] + v[1] + v[2] + v[3];
    float q = v[0]*v[0] + v[1]*v[1] + v[2]*v[2] + v[3]*v[3];
    #pragma unroll
    for (int d = 1; d < 64; d <<= 1) { s += __shfl_xor(s, d); q += __shfl_xor(q, d); }
    const float mu   = s * (1.0f / 256.0f);
    const float var  = fmaxf(q * (1.0f / 256.0f) - mu * mu, 0.0f);
    const float rstd = rsqrtf(var + 1e-5f);

    #pragma unroll
    for (int i = 0; i < 4; ++i) {
        const float o = (v[i] - mu) * rstd * loadf(g, lane * 4 + i, f32)
                      + loadf(b, lane * 4 + i, f32);
        if (PHASE == 0) hV1[base + i] = f2bf(o);
        else            storef(dout, base + i, f32, o);
    }
}

extern "C" void kernel_launch(void* const* d_in, const int* in_sizes, int n_in,
                              void* d_out, int out_size, void* d_ws, size_t ws_size,
                              hipStream_t stream)
{
    (void)d_ws; (void)ws_size; (void)in_sizes; (void)n_in; (void)out_size;
    const void* probe = d_in[0];

    // ---- Phase A: node message + node update ----
    msg_fused<0><<<dim3(2048), 256, 0, stream>>>(
        probe, d_in[0], d_in[1], d_in[2],
        d_in[3], d_in[4], d_in[5], d_in[6], d_in[7], d_in[8],
        nullptr, nullptr, d_out);
    ln_k<0><<<dim3(1024), 256, 0, stream>>>(probe, d_out, d_in[19], d_in[20]);

    // ---- Phase B: FFN ----
    gemm_ffn<0><<<dim3(64, 2), 256, 0, stream>>>(probe, d_out, d_in[15], d_in[16]);
    gemm_ffn<1><<<dim3(64, 1), 256, 0, stream>>>(probe, d_out, d_in[17], d_in[18]);
    ln_k<1><<<dim3(1024), 256, 0, stream>>>(probe, d_out, d_in[21], d_in[22]);

    // ---- Phase C: edge message + edge update (overwrites ALL of outE incl. scratch) ----
    msg_fused<1><<<dim3(2048), 256, 0, stream>>>(
        probe, d_out, d_in[1], d_in[2],
        d_in[9], d_in[10], d_in[11], d_in[12], d_in[13], d_in[14],
        d_in[23], d_in[24], d_out);
}